// Round 9
// baseline (205.727 us; speedup 1.0000x reference)
//
#include <hip/hip_runtime.h>

// ---------------------------------------------------------------------------
// Linformer self-attention, fp32 I/O, fp16 MFMA internally, MI355X (gfx950)
// b=4 n=4096 d=1024 h=16 dh=64 k=256  (no 1/sqrt(dh) scale per reference)
//
// Key algebra: proj_k^T (X Wk) == (proj_k^T X) Wk  -> K/V paths cost 4x less.
// stage1 v3: block = ALL 256 kk x 64 dd (X fetched exactly once), 8-way
// n-split (z = c*4+b, 32 z), f16 partials in the Qh region, f32-accum reduce.
// ---------------------------------------------------------------------------

typedef __fp16 f16x8 __attribute__((ext_vector_type(8)));
typedef __fp16 f16x2 __attribute__((ext_vector_type(2)));
typedef float fl4 __attribute__((ext_vector_type(4)));
typedef float f32x4 __attribute__((ext_vector_type(4)));
typedef unsigned int u32x2 __attribute__((ext_vector_type(2)));
typedef unsigned int u32x4 __attribute__((ext_vector_type(4)));

#define MFMA16(a, b, c) __builtin_amdgcn_mfma_f32_16x16x32_f16((a), (b), (c), 0, 0, 0)

__device__ __forceinline__ unsigned int pk2u(float a, float b) {
  f16x2 p = __builtin_amdgcn_cvt_pkrtz(a, b);  // low = a, high = b
  return __builtin_bit_cast(unsigned int, p);
}

__device__ __forceinline__ f16x8 pk8(fl4 a, fl4 b) {
  f16x2 p0 = __builtin_amdgcn_cvt_pkrtz(a[0], a[1]);
  f16x2 p1 = __builtin_amdgcn_cvt_pkrtz(a[2], a[3]);
  f16x2 p2 = __builtin_amdgcn_cvt_pkrtz(b[0], b[1]);
  f16x2 p3 = __builtin_amdgcn_cvt_pkrtz(b[2], b[3]);
  f16x8 r;
  r[0] = p0[0]; r[1] = p0[1]; r[2] = p1[0]; r[3] = p1[1];
  r[4] = p2[0]; r[5] = p2[1]; r[6] = p3[0]; r[7] = p3[1];
  return r;
}

__device__ __forceinline__ void gload_lds16(const __fp16* g, void* lds_base) {
  __builtin_amdgcn_global_load_lds(
      (const __attribute__((address_space(1))) void*)g,
      (__attribute__((address_space(3))) void*)lds_base, 16, 0, 0);
}

// read a swizzled 64B-row tile fragment: logical chunk lg of `row`
__device__ __forceinline__ f16x8 rd_swz(const __fp16* base, int row, int lg) {
  return *(const f16x8*)((const char*)base + row * 64 +
                         ((lg ^ ((row >> 1) & 3)) * 16));
}

// ---------------------------------------------------------------------------
// Transpose + convert: in f32 [R][C] -> out f16 [C][R]. 32x32 tiles.
// ---------------------------------------------------------------------------
__global__ __launch_bounds__(256) void tr_cvt(
    const float* __restrict__ in, __fp16* __restrict__ out, int R, int C) {
  __shared__ float tile[32][33];
  const int t = threadIdx.x;
  const int c0 = blockIdx.x * 32, r0 = blockIdx.y * 32;
  {
    const int r = t >> 3, cg = (t & 7) * 4;
    fl4 v = *(const fl4*)(in + (size_t)(r0 + r) * C + c0 + cg);
    tile[r][cg] = v[0]; tile[r][cg + 1] = v[1];
    tile[r][cg + 2] = v[2]; tile[r][cg + 3] = v[3];
  }
  __syncthreads();
  {
    const int cc = t >> 3, rg = (t & 7) * 4;
    u32x2 p;
    p[0] = pk2u(tile[rg + 0][cc], tile[rg + 1][cc]);
    p[1] = pk2u(tile[rg + 2][cc], tile[rg + 3][cc]);
    *(u32x2*)(out + (size_t)(c0 + cc) * R + r0 + rg) = p;
  }
}

// ---------------------------------------------------------------------------
// Stage 1 v3: Pk16[z][kk][dd] = sum_{n in 512-chunk c} pkT[kk][n]*X[b][n][dd]
// (z = c*4+b, c in [0,8)). Block = 256 kk x 64 dd; wave w = kk [w*64,w*64+64).
// Grid (32 z, 16 dd) -> all dd-blocks of a z on one XCD (pkT L2 reuse).
// Ak/Av: 4x gload_lds per tensor per iter (bt64 source-swizzle, 64-row
// groups). Bt (X^T): verified u32 transpose-write pattern. 16 iters.
// ---------------------------------------------------------------------------
__global__ __launch_bounds__(256) void stage1_partial(
    const __fp16* __restrict__ pkT,  // [256][4096]
    const __fp16* __restrict__ pvT,  // [256][4096]
    const float* __restrict__ X,     // [b][4096][1024]
    __fp16* __restrict__ Pk,         // [32][256][1024] f16 partials
    __fp16* __restrict__ Pv) {       // [32][256][1024]
  __shared__ __fp16 Ak[256 * 32];  // 16KB, rows kk
  __shared__ __fp16 Av[256 * 32];  // 16KB
  __shared__ __fp16 Bt[64 * 32];   // 4KB, rows dd
  const int t = threadIdx.x;
  const int lane = t & 63, w = t >> 6;
  const int lr = lane & 15, lg = lane >> 4;
  const int z = blockIdx.x, b = z & 3, c = z >> 2;
  const int dd0 = blockIdx.y * 64;

  f32x4 acck[4][4], accv[4][4];
#pragma unroll
  for (int i = 0; i < 4; ++i)
#pragma unroll
    for (int j = 0; j < 4; ++j) {
      acck[i][j] = (f32x4){0.f, 0.f, 0.f, 0.f};
      accv[i][j] = (f32x4){0.f, 0.f, 0.f, 0.f};
    }

  // A gload: instruction i covers rows i*64 + w*16 + (lane>>2)
  const int arow = w * 16 + (lane >> 2);
  const int ach = (lane & 3) ^ ((lane >> 3) & 3);  // source chunk pre-swizzle
  const __fp16* pkSrc = pkT + (size_t)arow * 4096 + c * 512 + ach * 8;
  const __fp16* pvSrc = pvT + (size_t)arow * 4096 + c * 512 + ach * 8;
  // X staging: n-pair p = t>>4, dd-quad qd = t&15 (verified pattern)
  const int p = t >> 4, qd = t & 15;
  const int ppos = p ^ ((qd & 3) << 2);
  const float* xSrc =
      X + ((size_t)b * 4096 + c * 512 + 2 * p) * 1024 + dd0 + qd * 4;

  for (int it = 0; it < 16; ++it) {
    const int n0 = it * 32;
    fl4 x0 = *(const fl4*)(xSrc + (size_t)n0 * 1024);
    fl4 x1 = *(const fl4*)(xSrc + (size_t)n0 * 1024 + 1024);
    __syncthreads();
#pragma unroll
    for (int i = 0; i < 4; ++i) {
      gload_lds16(pkSrc + (size_t)i * 64 * 4096 + n0,
                  (char*)Ak + i * 4096 + w * 1024);
      gload_lds16(pvSrc + (size_t)i * 64 * 4096 + n0,
                  (char*)Av + i * 4096 + w * 1024);
    }
#pragma unroll
    for (int j = 0; j < 4; ++j)
      *(unsigned int*)((char*)Bt + (qd * 4 + j) * 64 + ppos * 4) =
          pk2u(x0[j], x1[j]);
    __syncthreads();

    f16x8 ak[4], av[4], bx[4];
#pragma unroll
    for (int i = 0; i < 4; ++i) {
      ak[i] = rd_swz(Ak, w * 64 + i * 16 + lr, lg);
      av[i] = rd_swz(Av, w * 64 + i * 16 + lr, lg);
    }
#pragma unroll
    for (int j = 0; j < 4; ++j) {
      const int dd = j * 16 + lr;
      bx[j] = *(const f16x8*)((const char*)Bt + dd * 64 +
                              ((lg ^ ((dd >> 2) & 3)) * 16));
    }
#pragma unroll
    for (int i = 0; i < 4; ++i)
#pragma unroll
      for (int j = 0; j < 4; ++j) {
        acck[i][j] = MFMA16(ak[i], bx[j], acck[i][j]);
        accv[i][j] = MFMA16(av[i], bx[j], accv[i][j]);
      }
  }

  __fp16* pkOut = Pk + (size_t)z * 256 * 1024;
  __fp16* pvOut = Pv + (size_t)z * 256 * 1024;
#pragma unroll
  for (int i = 0; i < 4; ++i)
#pragma unroll
    for (int j = 0; j < 4; ++j)
#pragma unroll
      for (int r = 0; r < 4; ++r) {
        const int row = w * 64 + i * 16 + lg * 4 + r;
        const int col = dd0 + j * 16 + lr;
        pkOut[(size_t)row * 1024 + col] = (__fp16)acck[i][j][r];
        pvOut[(size_t)row * 1024 + col] = (__fp16)accv[i][j][r];
      }
}

// ---------------------------------------------------------------------------
// Stage 1 reduce: Xk = f16(sum_{c<8} f32(Pk16[c*4+b])). 8 f16/thread.
// ---------------------------------------------------------------------------
__global__ __launch_bounds__(256) void stage1_reduce(
    const __fp16* __restrict__ Pk, const __fp16* __restrict__ Pv,
    __fp16* __restrict__ Xk, __fp16* __restrict__ Xv) {
  const size_t idx = ((size_t)blockIdx.x * 256 + threadIdx.x) * 8;
  const int b = (int)(idx >> 18);           // 262144 elems per batch slab
  const size_t rem = idx & 0x3FFFFu;
  float sk[8], sv[8];
#pragma unroll
  for (int j = 0; j < 8; ++j) { sk[j] = 0.f; sv[j] = 0.f; }
#pragma unroll
  for (int c = 0; c < 8; ++c) {
    const size_t off = (((size_t)(c * 4 + b)) << 18) + rem;
    f16x8 vk = *(const f16x8*)(Pk + off);
    f16x8 vv = *(const f16x8*)(Pv + off);
#pragma unroll
    for (int j = 0; j < 8; ++j) {
      sk[j] += (float)vk[j];
      sv[j] += (float)vv[j];
    }
  }
  f16x8 ok, ov;
#pragma unroll
  for (int j = 0; j < 8; ++j) {
    ok[j] = (__fp16)sk[j];
    ov[j] = (__fp16)sv[j];
  }
  *(f16x8*)(Xk + idx) = ok;
  *(f16x8*)(Xv + idx) = ov;
}

// ---------------------------------------------------------------------------
// Generic small BT-GEMM: C[i][j] (f16) = sum_e A[i][e] * B[j][e], E=1024.
// ---------------------------------------------------------------------------
__global__ __launch_bounds__(256) void bt64(
    const __fp16* __restrict__ A, long long bsA,
    const __fp16* __restrict__ B, long long bsB,
    __fp16* __restrict__ C, int ldC, long long bsC) {
  constexpr int E = 1024;
  __shared__ __fp16 As[64 * 32];
  __shared__ __fp16 Bs[64 * 32];
  const int t = threadIdx.x;
  const int lane = t & 63, w = t >> 6;
  const int lr = lane & 15, lg = lane >> 4;
  const int i0 = blockIdx.x * 64, j0 = blockIdx.y * 64;
  A += (size_t)blockIdx.z * (size_t)bsA;
  B += (size_t)blockIdx.z * (size_t)bsB;
  C += (size_t)blockIdx.z * (size_t)bsC;
  const int wr = (w >> 1) * 32, wc = (w & 1) * 32;

  f32x4 acc[2][2];
#pragma unroll
  for (int i = 0; i < 2; ++i)
#pragma unroll
    for (int j = 0; j < 2; ++j) acc[i][j] = (f32x4){0.f, 0.f, 0.f, 0.f};

  const int gl_row = w * 16 + (lane >> 2);
  const int gl_ch = (lane & 3) ^ ((lane >> 3) & 3);
  const __fp16* aSrc = A + (size_t)(i0 + gl_row) * E + gl_ch * 8;
  const __fp16* bSrc = B + (size_t)(j0 + gl_row) * E + gl_ch * 8;

  for (int e0 = 0; e0 < E; e0 += 32) {
    __syncthreads();
    gload_lds16(aSrc + e0, (char*)As + w * 1024);
    gload_lds16(bSrc + e0, (char*)Bs + w * 1024);
    __syncthreads();

    f16x8 af[2], bf[2];
#pragma unroll
    for (int i = 0; i < 2; ++i)
      af[i] = rd_swz(As, wr + i * 16 + lr, lg);
#pragma unroll
    for (int j = 0; j < 2; ++j)
      bf[j] = rd_swz(Bs, wc + j * 16 + lr, lg);
#pragma unroll
    for (int i = 0; i < 2; ++i)
#pragma unroll
      for (int j = 0; j < 2; ++j)
        acc[i][j] = MFMA16(af[i], bf[j], acc[i][j]);
  }

#pragma unroll
  for (int i = 0; i < 2; ++i)
#pragma unroll
    for (int j = 0; j < 2; ++j)
#pragma unroll
      for (int r = 0; r < 4; ++r) {
        const int row = i0 + wr + i * 16 + lg * 4 + r;
        const int col = j0 + wc + j * 16 + lr;
        C[(size_t)row * ldC + col] = (__fp16)acc[i][j][r];
      }
}

// ---------------------------------------------------------------------------
// Q-path GEMM: Qh[16384][1024] (f16) = X(f32) . WqT^T, 128x128 tile, BK=32.
// ---------------------------------------------------------------------------
__global__ __launch_bounds__(256) void gemm_q(
    const float* __restrict__ X,
    const __fp16* __restrict__ WT,   // [1024][1024], WT[n][k] = W[k][n]
    __fp16* __restrict__ Q) {
  constexpr int K = 1024, N = 1024;
  __shared__ __fp16 Xs[128 * 32];
  __shared__ __fp16 Ws[128 * 32];
  const int t = threadIdx.x;
  const int lane = t & 63, w = t >> 6;
  const int lr = lane & 15, lg = lane >> 4;
  const int m0 = blockIdx.x * 128, n0 = blockIdx.y * 128;
  const int wr = (w >> 1) * 64, wc = (w & 1) * 64;

  f32x4 acc[4][4];
#pragma unroll
  for (int i = 0; i < 4; ++i)
#pragma unroll
    for (int j = 0; j < 4; ++j) acc[i][j] = (f32x4){0.f, 0.f, 0.f, 0.f};

  const int xrow = t >> 2;
  const int xpos = (t & 3) ^ ((t >> 3) & 3);
  const float* xSrc1 = X + (size_t)(m0 + xrow) * K + (t & 3) * 8;
  const float* xSrc2 = xSrc1 + (size_t)64 * K;
  const int gl_row = w * 16 + (lane >> 2);
  const int gl_ch = (lane & 3) ^ ((lane >> 3) & 3);
  const __fp16* wSrc0 = WT + (size_t)(n0 + gl_row) * K + gl_ch * 8;
  const __fp16* wSrc1 = WT + (size_t)(n0 + 64 + gl_row) * K + gl_ch * 8;

  for (int k0 = 0; k0 < K; k0 += 32) {
    fl4 a0 = *(const fl4*)(xSrc1 + k0);
    fl4 a1 = *(const fl4*)(xSrc1 + k0 + 4);
    fl4 a2 = *(const fl4*)(xSrc2 + k0);
    fl4 a3 = *(const fl4*)(xSrc2 + k0 + 4);
    __syncthreads();
    gload_lds16(wSrc0 + k0, (char*)Ws + w * 1024);
    gload_lds16(wSrc1 + k0, (char*)Ws + 4096 + w * 1024);
    *(f16x8*)((char*)Xs + xrow * 64 + xpos * 16) = pk8(a0, a1);
    *(f16x8*)((char*)Xs + (64 + xrow) * 64 + xpos * 16) = pk8(a2, a3);
    __syncthreads();

    f16x8 af[4], bf[4];
#pragma unroll
    for (int i = 0; i < 4; ++i)
      af[i] = rd_swz(Xs, wr + i * 16 + lr, lg);
#pragma unroll
    for (int j = 0; j < 4; ++j)
      bf[j] = rd_swz(Ws, wc + j * 16 + lr, lg);
#pragma unroll
    for (int i = 0; i < 4; ++i)
#pragma unroll
      for (int j = 0; j < 4; ++j)
        acc[i][j] = MFMA16(af[i], bf[j], acc[i][j]);
  }

#pragma unroll
  for (int i = 0; i < 4; ++i)
#pragma unroll
    for (int j = 0; j < 4; ++j)
#pragma unroll
      for (int r = 0; r < 4; ++r) {
        const int row = m0 + wr + i * 16 + lg * 4 + r;
        const int col = n0 + wc + j * 16 + lr;
        Q[(size_t)row * N + col] = (__fp16)acc[i][j][r];
      }
}

// ---------------------------------------------------------------------------
// Attention v3: block = 4 waves, 128 Q-rows of one (b,h); grid 2048.
// 32KB LDS (K then V), swapped QK^T, in-register P via cvt_pk + ds_bpermute.
// ---------------------------------------------------------------------------
__global__ __launch_bounds__(256) void attn_k(
    const __fp16* __restrict__ Q,    // [b*4096][1024]
    const __fp16* __restrict__ Kp,   // [b][256][1024]
    const __fp16* __restrict__ Vpt,  // [b][1024][256]
    float* __restrict__ O) {         // [b*4096][1024] f32
  __shared__ __fp16 KV[256 * 64];    // 32KB: K tile, then V^T tile
  const int t = threadIdx.x;
  const int lane = t & 63, w = t >> 6;
  const int lr = lane & 15, lg = lane >> 4;
  const int bh = blockIdx.x >> 5, rb = blockIdx.x & 31;
  const int b = bh >> 4, h = bh & 15;
  const int m0 = rb * 128 + w * 32;

  const __fp16* Kph = Kp + (size_t)b * 256 * 1024 + h * 64;
  const __fp16* Vph = Vpt + ((size_t)b * 1024 + h * 64) * 256;
  const __fp16* Qh = Q + ((size_t)(b * 4096 + m0)) * 1024 + h * 64;

#pragma unroll
  for (int i = 0; i < 8; ++i) {
    const int kr = (i * 4 + w) * 8 + (lane >> 3);
    gload_lds16(Kph + (size_t)kr * 1024 + (((lane & 7) ^ (kr & 7)) * 8),
                (char*)KV + (i * 4 + w) * 1024);
  }

  f16x8 aq[2][2];
#pragma unroll
  for (int mi = 0; mi < 2; ++mi)
#pragma unroll
    for (int s = 0; s < 2; ++s)
      aq[mi][s] =
          *(const f16x8*)(Qh + (size_t)(mi * 16 + lr) * 1024 + s * 32 + lg * 8);

  __syncthreads();  // K staged

  f32x4 dots[2][16];
#pragma unroll
  for (int mi = 0; mi < 2; ++mi)
#pragma unroll
    for (int jt = 0; jt < 16; ++jt) dots[mi][jt] = (f32x4){0.f, 0.f, 0.f, 0.f};
#pragma unroll
  for (int jt = 0; jt < 16; ++jt) {
    const int r = jt * 16 + lr;
    f16x8 k0 = *(const f16x8*)((const char*)KV + r * 128 + ((lg ^ (r & 7)) * 16));
    f16x8 k1 =
        *(const f16x8*)((const char*)KV + r * 128 + (((4 + lg) ^ (r & 7)) * 16));
    dots[0][jt] = MFMA16(k0, aq[0][0], dots[0][jt]);
    dots[0][jt] = MFMA16(k1, aq[0][1], dots[0][jt]);
    dots[1][jt] = MFMA16(k0, aq[1][0], dots[1][jt]);
    dots[1][jt] = MFMA16(k1, aq[1][1], dots[1][jt]);
  }

  unsigned cpk[2][16][2];
  float smv[2];
#pragma unroll
  for (int mi = 0; mi < 2; ++mi) {
    float mx = -1e30f;
#pragma unroll
    for (int jt = 0; jt < 16; ++jt)
#pragma unroll
      for (int r = 0; r < 4; ++r) mx = fmaxf(mx, dots[mi][jt][r]);
    mx = fmaxf(mx, __shfl_xor(mx, 16, 64));
    mx = fmaxf(mx, __shfl_xor(mx, 32, 64));
    float sm = 0.f;
#pragma unroll
    for (int jt = 0; jt < 16; ++jt) {
#pragma unroll
      for (int r = 0; r < 4; ++r) {
        float p = __expf(dots[mi][jt][r] - mx);
        dots[mi][jt][r] = p;
        sm += p;
      }
      cpk[mi][jt][0] = pk2u(dots[mi][jt][0], dots[mi][jt][1]);
      cpk[mi][jt][1] = pk2u(dots[mi][jt][2], dots[mi][jt][3]);
    }
    sm += __shfl_xor(sm, 16, 64);
    sm += __shfl_xor(sm, 32, 64);
    smv[mi] = sm;
  }

  __syncthreads();  // all waves done reading K

#pragma unroll
  for (int i = 0; i < 8; ++i) {
    const int dd = (i * 4 + w) * 2 + (lane >> 5);
    gload_lds16(Vph + (size_t)dd * 256 + (((lane & 31) ^ (dd & 7)) * 8),
                (char*)KV + (i * 4 + w) * 1024);
  }
  __syncthreads();  // V staged

#pragma unroll
  for (int mi = 0; mi < 2; ++mi) {
    f32x4 o[4];
#pragma unroll
    for (int j = 0; j < 4; ++j) o[j] = (f32x4){0.f, 0.f, 0.f, 0.f};
#pragma unroll
    for (int ks = 0; ks < 8; ++ks) {
      u32x4 wds;
#pragma unroll
      for (int m = 0; m < 4; ++m) {
        const int addr = ((((lane & 16) >> 3) + (m >> 1)) * 16 + lr) * 4;
        const int a0 = __builtin_amdgcn_ds_bpermute(
            addr, (int)cpk[mi][ks * 2][m & 1]);
        const int a1 = __builtin_amdgcn_ds_bpermute(
            addr, (int)cpk[mi][ks * 2 + 1][m & 1]);
        wds[m] = (unsigned)((lg >> 1) ? a1 : a0);
      }
      f16x8 pa = __builtin_bit_cast(f16x8, wds);
#pragma unroll
      for (int jt2 = 0; jt2 < 4; ++jt2) {
        const int dd = jt2 * 16 + lr;
        f16x8 bv = *(const f16x8*)((const char*)KV + dd * 512 +
                                   (((ks * 4 + lg) ^ (dd & 7)) * 16));
        o[jt2] = MFMA16(pa, bv, o[jt2]);
      }
    }

    float rs[4];
#pragma unroll
    for (int r = 0; r < 4; ++r)
      rs[r] = 1.f / __shfl(smv[mi], (lane & 48) + lg * 4 + r, 64);
#pragma unroll
    for (int jt2 = 0; jt2 < 4; ++jt2)
#pragma unroll
      for (int r = 0; r < 4; ++r) {
        const size_t row = (size_t)(b * 4096 + m0 + mi * 16 + lg * 4 + r);
        O[row * 1024 + h * 64 + jt2 * 16 + lr] = o[jt2][r] * rs[r];
      }
  }
}

// ---------------------------------------------------------------------------
extern "C" void kernel_launch(void* const* d_in, const int* in_sizes, int n_in,
                              void* d_out, int out_size, void* d_ws, size_t ws_size,
                              hipStream_t stream) {
  (void)in_sizes; (void)n_in; (void)out_size; (void)ws_size;
  const float* x  = (const float*)d_in[0];
  const float* Wq = (const float*)d_in[1];
  const float* Wk = (const float*)d_in[2];
  const float* Wv = (const float*)d_in[3];
  const float* pk = (const float*)d_in[4];
  const float* pv = (const float*)d_in[5];
  float* out = (float*)d_out;

  // ws layout (f16 halfwords), total ~52.4 MB.
  // The Qh region (33.5 MB) doubles as the f16 partials (Pk16+Pv16 = 33.5 MB)
  // for stage1; gemm_q overwrites it later (stream-ordered after reduce).
  __fp16* Qh  = (__fp16*)d_ws;                       // 16384*1024 f16
  __fp16* WqT = Qh  + (size_t)16384 * 1024;          // 1024*1024 each
  __fp16* WkT = WqT + (size_t)1024 * 1024;
  __fp16* WvT = WkT + (size_t)1024 * 1024;
  __fp16* pkT = WvT + (size_t)1024 * 1024;           // 256*4096 each
  __fp16* pvT = pkT + (size_t)256 * 4096;
  __fp16* Xk  = pvT + (size_t)256 * 4096;            // 4*256*1024 each
  __fp16* Xv  = Xk  + (size_t)4 * 256 * 1024;
  __fp16* Kp  = Xv  + (size_t)4 * 256 * 1024;
  __fp16* Vpt = Kp  + (size_t)4 * 256 * 1024;
  __fp16* Pk16 = (__fp16*)d_ws;                      // 32*256*1024 f16 each
  __fp16* Pv16 = Pk16 + (size_t)32 * 256 * 1024;

  const dim3 bb(256);

  // 0. one-time transposes (f32 -> f16)
  tr_cvt<<<dim3(32, 32), bb, 0, stream>>>(Wq, WqT, 1024, 1024);
  tr_cvt<<<dim3(32, 32), bb, 0, stream>>>(Wk, WkT, 1024, 1024);
  tr_cvt<<<dim3(32, 32), bb, 0, stream>>>(Wv, WvT, 1024, 1024);
  tr_cvt<<<dim3(8, 128), bb, 0, stream>>>(pk, pkT, 4096, 256);
  tr_cvt<<<dim3(8, 128), bb, 0, stream>>>(pv, pvT, 4096, 256);

  // 1. split-K low-rank projections of X + reduce
  stage1_partial<<<dim3(32, 16), bb, 0, stream>>>(pkT, pvT, x, Pk16, Pv16);
  stage1_reduce<<<dim3(512), bb, 0, stream>>>(Pk16, Pv16, Xk, Xv);

  // 2. Kp = Xk . Wk ; VpT = (Xv . Wv)^T
  bt64<<<dim3(4, 16, 4), bb, 0, stream>>>(Xk, 256LL * 1024, WkT, 0LL,
                                          Kp, 1024, 256LL * 1024);
  bt64<<<dim3(16, 4, 4), bb, 0, stream>>>(WvT, 0LL, Xv, 256LL * 1024,
                                          Vpt, 256, 1024LL * 256);

  // 3. Q projection (overwrites partials region - stream-ordered)
  gemm_q<<<dim3(128, 8), bb, 0, stream>>>(x, WqT, Qh);

  // 4. attention (32KB LDS, swapped QK, in-register P)
  attn_k<<<dim3(2048), bb, 0, stream>>>(Qh, Kp, Vpt, out);
}